// Round 1
// 479.818 us; speedup vs baseline: 1.0314x; 1.0314x over previous
//
#include <hip/hip_runtime.h>
#include <hip/hip_bf16.h>

#define O_DIM 8192
#define I_DIM 8192
#define G_DIM 64
#define RANK  128

typedef __bf16 bf16x8 __attribute__((ext_vector_type(8)));
typedef __bf16 bf16x4 __attribute__((ext_vector_type(4)));
typedef float  f32x4  __attribute__((ext_vector_type(4)));

// ---- pre-pass 1: svd_up [8192 x 128] f32 -> bf16, same layout ----
__global__ void k_convert_up(const float* __restrict__ up, __bf16* __restrict__ A_bf) {
    size_t t = (size_t)blockIdx.x * blockDim.x + threadIdx.x;   // 262144 threads, 4 elems each
    const float4* in4 = (const float4*)up;
    float4 v = in4[t];
    bf16x4 o = { (__bf16)v.x, (__bf16)v.y, (__bf16)v.z, (__bf16)v.w };
    *(bf16x4*)(A_bf + 4 * t) = o;
}

// ---- pre-pass 2: svd_down [128 x 8192] f32 -> Bt [8192 x 128] bf16 (transposed) ----
__global__ void k_transpose_down(const float* __restrict__ down, __bf16* __restrict__ Bt) {
    __shared__ __bf16 tile[64][132];        // +4 pad keeps 8B alignment, breaks bank stride
    int tid = threadIdx.x;
    int ib  = blockIdx.x * 64;              // i-range of this block
    int il  = tid & 63;
    int k4  = tid >> 6;
    for (int kk = 0; kk < 32; ++kk) {
        int k = kk * 4 + k4;
        tile[il][k] = (__bf16)down[(size_t)k * I_DIM + ib + il];   // coalesced 256B reads
    }
    __syncthreads();
    // output region is contiguous: Bt[ib*128 .. (ib+64)*128)
    uint2* dst = (uint2*)(Bt + (size_t)ib * RANK);
    #pragma unroll
    for (int jj = 0; jj < 8; ++jj) {
        int f   = (jj * 256 + tid) * 4;     // element index, multiple of 4
        int i_l = f >> 7;
        int k_l = f & 127;
        dst[jj * 256 + tid] = *(const uint2*)&tile[i_l][k_l];      // coalesced 8B writes
    }
}

// ---- main fused kernel: one block = 128x128 output tile (one scale-group wide) ----
// Weight tile (64 KB) is DMA'd into LDS via global_load_lds at block start so its
// HBM latency hides under the MFMA section; ~16 KB in flight per wave (zero VGPR
// cost) vs ~64 B with the old scalar-register loads -> fetch goes BW-bound.
__global__ __launch_bounds__(256, 2)
void k_main(const int* __restrict__ weight, const float* __restrict__ scale,
            const float* __restrict__ zp, const __bf16* __restrict__ A_bf,
            const __bf16* __restrict__ Bt_bf, float* __restrict__ out) {
    __shared__ int w_lds[128 * 128];        // exactly 64 KB -> 2 blocks/CU
    int tid = threadIdx.x;
    int g       = blockIdx.x;               // column group == scale group (tile width 128 == GS)
    int rowbase = blockIdx.y * 128;
    int colbase = g * 128;

    int w    = tid >> 6;
    int lane = tid & 63;

    // ---- issue async weight-tile DMA FIRST: 64 x 1KB global_load_lds dwordx4 ----
    // LDS is linear row-major [128][128]; instr j fills elements [j*256, j*256+256)
    // = rows {2j, 2j+1}. Lane l supplies global addr for its 16B slot:
    //   elem = j*256 + l*4  ->  row = 2j + (l>>5), col = (l&31)*4
    // NOTE: no __syncthreads() before this point (a barrier would drain vmcnt
    // and kill the overlap).
    {
        const int* gsrc = weight + (size_t)(rowbase + (lane >> 5)) * I_DIM
                        + colbase + ((lane & 31) * 4);
        #pragma unroll
        for (int jj = 0; jj < 16; ++jj) {
            int j = w * 16 + jj;            // wave w owns rows [w*32, w*32+32)
            __builtin_amdgcn_global_load_lds(
                (const __attribute__((address_space(1))) void*)(gsrc + (size_t)(2 * j) * I_DIM),
                (__attribute__((address_space(3))) void*)(&w_lds[j * 256]),
                16, 0, 0);
        }
    }

    int l15  = lane & 15;
    int quad = lane >> 4;
    int wrow = (w >> 1) * 64;               // wave's 64x64 quadrant
    int wcol = (w & 1) * 64;
    int orow0 = wrow + quad * 4;            // local row base; + rb*16 + r

    // ---- scale/zp into registers (replaces the old LDS staging + its barrier) ----
    // 16 lanes (l15) share each address -> coalesces to 4 addrs per wave-instr; L2-hot.
    float sv[16], zv[16];
    #pragma unroll
    for (int i = 0; i < 16; ++i) {
        int row = rowbase + orow0 + (i >> 2) * 16 + (i & 3);
        sv[i] = scale[(size_t)row * G_DIM + g];
        zv[i] = zp[(size_t)row * G_DIM + g];
    }

    // A-frag: A[m=lane&15][k=quad*8+j]  (m89/m120 measured layout)
    const __bf16* Ap = A_bf  + (size_t)(rowbase + wrow + l15) * RANK + quad * 8;
    const __bf16* Bp = Bt_bf + (size_t)(colbase + wcol + l15) * RANK + quad * 8;

    f32x4 acc[4][4];
    #pragma unroll
    for (int rb = 0; rb < 4; ++rb)
        #pragma unroll
        for (int cb = 0; cb < 4; ++cb)
            acc[rb][cb] = (f32x4){0.f, 0.f, 0.f, 0.f};

    #pragma unroll
    for (int kc = 0; kc < 4; ++kc) {    // K = 128 = 4 chunks of 32
        bf16x8 af[4], bfr[4];
        #pragma unroll
        for (int rb = 0; rb < 4; ++rb)
            af[rb] = *(const bf16x8*)(Ap + rb * 16 * RANK + kc * 32);
        #pragma unroll
        for (int cb = 0; cb < 4; ++cb)
            bfr[cb] = *(const bf16x8*)(Bp + cb * 16 * RANK + kc * 32);
        #pragma unroll
        for (int rb = 0; rb < 4; ++rb)
            #pragma unroll
            for (int cb = 0; cb < 4; ++cb)
                acc[rb][cb] = __builtin_amdgcn_mfma_f32_16x16x32_bf16(
                    af[rb], bfr[cb], acc[rb][cb], 0, 0, 0);
    }

    // single barrier: compiler emits s_waitcnt vmcnt(0) before s_barrier, which is
    // exactly the drain we need -> all waves' weight DMAs landed in LDS.
    __syncthreads();

    // epilogue: dequant from LDS + add correction, stream to out.
    // ds_read_b32 pattern: bank = col%32, 16 cols x 4 quads -> 4-way conflict
    // (1.58x, ~600 cy/wave) - negligible vs the per-tile memory budget.
    int    widx = orow0 * 128 + wcol + l15;
    size_t base = (size_t)(rowbase + orow0) * I_DIM + colbase + wcol + l15;
    #pragma unroll
    for (int rb = 0; rb < 4; ++rb) {
        #pragma unroll
        for (int r = 0; r < 4; ++r) {
            float s = sv[rb * 4 + r];
            float z = zv[rb * 4 + r];
            #pragma unroll
            for (int cb = 0; cb < 4; ++cb) {
                float v = fmaf((float)w_lds[widx + (rb * 16 + r) * 128 + cb * 16], s, z)
                        + acc[rb][cb][r];
                out[base + (size_t)(rb * 16 + r) * I_DIM + cb * 16] = v;
            }
        }
    }
}

extern "C" void kernel_launch(void* const* d_in, const int* in_sizes, int n_in,
                              void* d_out, int out_size, void* d_ws, size_t ws_size,
                              hipStream_t stream) {
    const int*   weight = (const int*)d_in[0];
    const float* scale  = (const float*)d_in[1];
    const float* zp     = (const float*)d_in[2];
    const float* up     = (const float*)d_in[3];
    const float* down   = (const float*)d_in[4];
    float* out = (float*)d_out;

    __bf16* A_bf  = (__bf16*)d_ws;                  // 8192*128 bf16 = 2 MB
    __bf16* Bt_bf = A_bf + (size_t)O_DIM * RANK;    // 8192*128 bf16 = 2 MB

    k_convert_up<<<1024, 256, 0, stream>>>(up, A_bf);
    k_transpose_down<<<128, 256, 0, stream>>>(down, Bt_bf);

    dim3 grid(64, 64);   // x = column group (g), y = row tile
    k_main<<<grid, 256, 0, stream>>>(weight, scale, zp, A_bf, Bt_bf, out);
}